// Round 3
// baseline (482.281 us; speedup 1.0000x reference)
//
#include <hip/hip_runtime.h>
#include <hip/hip_bf16.h>

#define D_MODEL 4096
#define NFIB    64
#define NBATCH  4
#define LSEQ    4096
#define TM      16
#define TILES   (LSEQ / TM)   // 256

typedef __attribute__((ext_vector_type(4))) float f32x4;
typedef __attribute__((ext_vector_type(8))) short bf16x8;

__device__ __forceinline__ unsigned short f2bf(float f) {
  unsigned int u = __builtin_bit_cast(unsigned int, f);
  u += 0x7FFFu + ((u >> 16) & 1u);   // round-to-nearest-even
  return (unsigned short)(u >> 16);
}

__device__ __forceinline__ bf16x8 cvt8(f32x4 a, f32x4 b) {
  union { __hip_bfloat162 h2[4]; bf16x8 v; } u;
  u.h2[0] = __float22bfloat162_rn(make_float2(a[0], a[1]));
  u.h2[1] = __float22bfloat162_rn(make_float2(a[2], a[3]));
  u.h2[2] = __float22bfloat162_rn(make_float2(b[0], b[1]));
  u.h2[3] = __float22bfloat162_rn(make_float2(b[2], b[3]));
  return u.v;
}

// ---------------------------------------------------------------------------
// S_b = Q_b - I = 2 (I - A_b)^{-1} A_b  via Gauss-Jordan on [I-A | 2A].
// 256 threads: k = col (64), g = row-group (4x16 rows).
// ---------------------------------------------------------------------------
__global__ __launch_bounds__(256) void cayley_kernel(const float* __restrict__ A,
                                                     float* __restrict__ S) {
  __shared__ float M[64][66];
  __shared__ float R[64][66];
  const int b = blockIdx.x;
  const int tid = threadIdx.x;
  const int k = tid & 63;
  const int g = tid >> 6;
  const float* Ab = A + b * 4096;
#pragma unroll
  for (int ii = 0; ii < 16; ++ii) {
    int i = g * 16 + ii;
    float a = Ab[i * 64 + k];
    M[i][k] = ((i == k) ? 1.0f : 0.0f) - a;
    R[i][k] = 2.0f * a;
  }
  __syncthreads();
  for (int j = 0; j < 64; ++j) {
    float inv = 1.0f / M[j][j];
    __syncthreads();
    if (g == 0) { M[j][k] *= inv; R[j][k] *= inv; }
    __syncthreads();
    float mjk = M[j][k], rjk = R[j][k];
    float f[16];
#pragma unroll
    for (int ii = 0; ii < 16; ++ii) f[ii] = M[g * 16 + ii][j];
    __syncthreads();
#pragma unroll
    for (int ii = 0; ii < 16; ++ii) {
      int i = g * 16 + ii;
      if (i != j) {
        M[i][k] -= f[ii] * mjk;
        R[i][k] -= f[ii] * rjk;
      }
    }
    __syncthreads();
  }
  float* Sb = S + b * 4096;
#pragma unroll
  for (int ii = 0; ii < 16; ++ii) {
    int i = g * 16 + ii;
    Sb[i * 64 + k] = R[i][k];
  }
}

// ---------------------------------------------------------------------------
// Wd2[((ks*4+nf)*64 + lane)*8 + j] = bf16(Wd[(nf*16 + lane&15)][ks*32 + (lane>>4)*8 + j])
// -> per (ks, wave-fiber-tile nf) a wave's B-fragment load is 1KB contiguous.
// ---------------------------------------------------------------------------
__global__ void cvt_wd_kernel(const float* __restrict__ Wd, unsigned short* __restrict__ Wd2) {
  int idx = blockIdx.x * 256 + threadIdx.x;   // 0..262143
  int j    = idx & 7;
  int lane = (idx >> 3) & 63;
  int nf   = (idx >> 9) & 3;
  int ks   = idx >> 11;
  int row = nf * 16 + (lane & 15);
  int col = ks * 32 + (lane >> 4) * 8 + j;
  Wd2[idx] = f2bf(Wd[row * D_MODEL + col]);
}

// ---------------------------------------------------------------------------
// U2[(((b*256+nt)*64 + lane)*2 + h)*8 + j] =
//   bf16( alpha * sum_g Wup[d][g] * S[b][g][f] ),  d = nt*16 + (lane&15),
//   f = h*32 + (lane>>4)*8 + j.  S_b staged in LDS; W_up row vectorized.
// ---------------------------------------------------------------------------
__global__ __launch_bounds__(256) void prep_u_kernel(const float* __restrict__ Wup,
                                                     const float* __restrict__ S,
                                                     const float* __restrict__ alpha_p,
                                                     unsigned short* __restrict__ U2) {
  __shared__ float Sl[4096];
  const int idx0 = blockIdx.x * 256;
  const int b = idx0 >> 18;
  const float* Sb = S + b * 4096;
  for (int i = threadIdx.x; i < 1024; i += 256)
    ((f32x4*)Sl)[i] = ((const f32x4*)Sb)[i];
  __syncthreads();

  const int idx = idx0 + threadIdx.x;
  const int j    = idx & 7;
  const int h    = (idx >> 3) & 1;
  const int lane = (idx >> 4) & 63;
  const int nt   = (idx >> 10) & 255;
  const int d = nt * 16 + (lane & 15);
  const int f = h * 32 + (lane >> 4) * 8 + j;
  const float alpha = alpha_p[0];
  const f32x4* wr = (const f32x4*)(Wup + d * 64);
  float s = 0.f;
#pragma unroll
  for (int g4 = 0; g4 < 16; ++g4) {
    f32x4 wv = wr[g4];
    s += wv[0] * Sl[(g4 * 4 + 0) * 64 + f] + wv[1] * Sl[(g4 * 4 + 1) * 64 + f] +
         wv[2] * Sl[(g4 * 4 + 2) * 64 + f] + wv[3] * Sl[(g4 * 4 + 3) * 64 + f];
  }
  U2[idx] = f2bf(alpha * s);
}

// ---------------------------------------------------------------------------
// Fused main kernel. Block = 16 tokens, 256 threads (4 waves), no phase-1 LDS.
// Phase 1: F = H_tile @ Wd^T. Each lane loads its own A-fragment straight
//          from H (32B contiguous per lane); B-fragments from pre-swizzled
//          Wd2 (1KB contiguous per wave per step, L2-hot). Wave w owns
//          fibers w*16..w*16+15. 128 independent steps, deeply pipelined.
// Phase 2: Out = H + F @ U^T with pre-swizzled U2.
// ---------------------------------------------------------------------------
__global__ __launch_bounds__(256, 4) void main_kernel(
    const float* __restrict__ H, const unsigned short* __restrict__ Wd2,
    const unsigned short* __restrict__ U2, float* __restrict__ Out) {
  const int blk = blockIdx.x;
  const int b = blk >> 8;
  const int t = blk & 255;
  const int row0 = b * LSEQ + t * TM;

  const int tid = threadIdx.x;
  const int w = tid >> 6, l = tid & 63, lr = l & 15, lq = l >> 4;

  __shared__ __attribute__((aligned(16))) unsigned short Fb[TM][72];

  // ---------------- Phase 1 (no LDS, no barriers) ----------------
  const float* ha = H + (size_t)(row0 + lr) * D_MODEL + lq * 8;
  const unsigned short* wb = Wd2 + w * 512 + l * 8;

  f32x4 acc = {0, 0, 0, 0};
#pragma unroll 4
  for (int s = 0; s < 128; ++s) {
    f32x4 h0 = *(const f32x4*)(ha + s * 32);
    f32x4 h1 = *(const f32x4*)(ha + s * 32 + 4);
    bf16x8 bfr = *(const bf16x8*)(wb + (size_t)s * 2048);
    bf16x8 afr = cvt8(h0, h1);
    acc = __builtin_amdgcn_mfma_f32_16x16x32_bf16(afr, bfr, acc, 0, 0, 0);
  }

  // F (this wave's 16-fiber strip) -> LDS bf16
  Fb[lq * 4 + 0][w * 16 + lr] = f2bf(acc[0]);
  Fb[lq * 4 + 1][w * 16 + lr] = f2bf(acc[1]);
  Fb[lq * 4 + 2][w * 16 + lr] = f2bf(acc[2]);
  Fb[lq * 4 + 3][w * 16 + lr] = f2bf(acc[3]);
  __syncthreads();

  // ---------------- Phase 2 ----------------
  bf16x8 fa0 = *(const bf16x8*)(&Fb[lr][lq * 8]);
  bf16x8 fa1 = *(const bf16x8*)(&Fb[lr][32 + lq * 8]);

  const unsigned short* ub = U2 + (((size_t)(b * 256) + w * 64) * 64 + l) * 16;
  const int nbase = w * 1024;
#pragma unroll 4
  for (int nf = 0; nf < 64; ++nf) {
    const unsigned short* up = ub + (size_t)nf * 1024;
    bf16x8 u0 = *(const bf16x8*)(up);
    bf16x8 u1 = *(const bf16x8*)(up + 8);
    f32x4 c = {0, 0, 0, 0};
    c = __builtin_amdgcn_mfma_f32_16x16x32_bf16(fa0, u0, c, 0, 0, 0);
    c = __builtin_amdgcn_mfma_f32_16x16x32_bf16(fa1, u1, c, 0, 0, 0);
    const int n = nbase + nf * 16;
#pragma unroll
    for (int rr = 0; rr < 4; ++rr) {
      size_t o = (size_t)(row0 + lq * 4 + rr) * D_MODEL + n + lr;
      Out[o] = H[o] + c[rr];
    }
  }
}

// ---------------------------------------------------------------------------
extern "C" void kernel_launch(void* const* d_in, const int* in_sizes, int n_in,
                              void* d_out, int out_size, void* d_ws, size_t ws_size,
                              hipStream_t stream) {
  const float* h_t    = (const float*)d_in[0];
  // d_in[1] = z0 (unused by the reference)
  const float* A_u    = (const float*)d_in[2];
  const float* alpha  = (const float*)d_in[3];
  const float* W_down = (const float*)d_in[4];
  const float* W_up   = (const float*)d_in[5];
  float* out = (float*)d_out;

  char* ws = (char*)d_ws;
  float*          S   = (float*)ws;                              // 4*64*64*4   = 64 KiB
  unsigned short* Wd2 = (unsigned short*)(ws + 65536);           // 64*4096*2   = 512 KiB
  unsigned short* U2  = (unsigned short*)(ws + 65536 + 524288);  // 4*4096*64*2 = 2 MiB

  cayley_kernel<<<NBATCH, 256, 0, stream>>>(A_u, S);
  cvt_wd_kernel<<<(NFIB * D_MODEL) / 256, 256, 0, stream>>>(W_down, Wd2);
  prep_u_kernel<<<(NBATCH * D_MODEL * NFIB) / 256, 256, 0, stream>>>(W_up, S, alpha, U2);
  main_kernel<<<NBATCH * TILES, 256, 0, stream>>>(h_t, Wd2, U2, out);
}

// Round 4
// 307.574 us; speedup vs baseline: 1.5680x; 1.5680x over previous
//
#include <hip/hip_runtime.h>
#include <hip/hip_bf16.h>

#define D_MODEL 4096
#define NFIB    64
#define NBATCH  4
#define LSEQ    4096
#define TM      16
#define TILES   (LSEQ / TM)   // 256

typedef __attribute__((ext_vector_type(4))) float f32x4;
typedef __attribute__((ext_vector_type(8))) short bf16x8;

__device__ __forceinline__ unsigned short f2bf(float f) {
  unsigned int u = __builtin_bit_cast(unsigned int, f);
  u += 0x7FFFu + ((u >> 16) & 1u);   // round-to-nearest-even
  return (unsigned short)(u >> 16);
}

__device__ __forceinline__ bf16x8 cvt8(f32x4 a, f32x4 b) {
  union { __hip_bfloat162 h2[4]; bf16x8 v; } u;
  u.h2[0] = __float22bfloat162_rn(make_float2(a[0], a[1]));
  u.h2[1] = __float22bfloat162_rn(make_float2(a[2], a[3]));
  u.h2[2] = __float22bfloat162_rn(make_float2(b[0], b[1]));
  u.h2[3] = __float22bfloat162_rn(make_float2(b[2], b[3]));
  return u.v;
}

// ---------------------------------------------------------------------------
// S_b = Q_b - I = 2 (I - A_b)^{-1} A_b. Gauss-Jordan WITHOUT pivot
// normalization (2 barriers/pivot), final diagonal scale.
// ---------------------------------------------------------------------------
__global__ __launch_bounds__(256) void cayley_kernel(const float* __restrict__ A,
                                                     float* __restrict__ S) {
  __shared__ float M[64][66];
  __shared__ float R[64][66];
  const int b = blockIdx.x;
  const int tid = threadIdx.x;
  const int k = tid & 63;
  const int g = tid >> 6;
  const float* Ab = A + b * 4096;
#pragma unroll
  for (int ii = 0; ii < 16; ++ii) {
    int i = g * 16 + ii;
    float a = Ab[i * 64 + k];
    M[i][k] = ((i == k) ? 1.0f : 0.0f) - a;
    R[i][k] = 2.0f * a;
  }
  for (int j = 0; j < 64; ++j) {
    __syncthreads();
    float pr  = 1.0f / M[j][j];
    float mjk = M[j][k], rjk = R[j][k];
    float f[16];
#pragma unroll
    for (int ii = 0; ii < 16; ++ii) f[ii] = M[g * 16 + ii][j] * pr;
    __syncthreads();
#pragma unroll
    for (int ii = 0; ii < 16; ++ii) {
      int i = g * 16 + ii;
      if (i != j) { M[i][k] -= f[ii] * mjk; R[i][k] -= f[ii] * rjk; }
    }
  }
  __syncthreads();
  float* Sb = S + b * 4096;
#pragma unroll
  for (int ii = 0; ii < 16; ++ii) {
    int i = g * 16 + ii;
    Sb[i * 64 + k] = R[i][k] / M[i][i];
  }
}

// ---------------------------------------------------------------------------
// Merged prep: blocks [0,1024) convert W_down into the wave-swizzled Wd2
// layout; blocks [1024,5120) build U2 = alpha * Wup @ S in the phase-2
// swizzled layout.
// ---------------------------------------------------------------------------
__global__ __launch_bounds__(256) void prep_kernel(const float* __restrict__ Wd,
                                                   const float* __restrict__ Wup,
                                                   const float* __restrict__ S,
                                                   const float* __restrict__ alpha_p,
                                                   unsigned short* __restrict__ Wd2,
                                                   unsigned short* __restrict__ U2) {
  const int blk = blockIdx.x;
  if (blk < 1024) {
    // Wd2[((ks*4+nf)*64 + lane)*8 + j] = bf16(Wd[nf*16+(lane&15)][ks*32+(lane>>4)*8+j])
    int idx = blk * 256 + threadIdx.x;
    int j    = idx & 7;
    int lane = (idx >> 3) & 63;
    int nf   = (idx >> 9) & 3;
    int ks   = idx >> 11;
    int row = nf * 16 + (lane & 15);
    int col = ks * 32 + (lane >> 4) * 8 + j;
    Wd2[idx] = f2bf(Wd[row * D_MODEL + col]);
  } else {
    __shared__ float Sl[4096];
    const int idx0 = (blk - 1024) * 256;
    const int b = idx0 >> 18;
    const float* Sb = S + b * 4096;
    for (int i = threadIdx.x; i < 1024; i += 256)
      ((f32x4*)Sl)[i] = ((const f32x4*)Sb)[i];
    __syncthreads();
    const int idx = idx0 + threadIdx.x;
    const int j    = idx & 7;
    const int h    = (idx >> 3) & 1;
    const int lane = (idx >> 4) & 63;
    const int nt   = (idx >> 10) & 255;
    const int d = nt * 16 + (lane & 15);
    const int f = h * 32 + (lane >> 4) * 8 + j;
    const float alpha = alpha_p[0];
    const f32x4* wr = (const f32x4*)(Wup + d * 64);
    float s = 0.f;
#pragma unroll
    for (int g4 = 0; g4 < 16; ++g4) {
      f32x4 wv = wr[g4];
      s += wv[0] * Sl[(g4 * 4 + 0) * 64 + f] + wv[1] * Sl[(g4 * 4 + 1) * 64 + f] +
           wv[2] * Sl[(g4 * 4 + 2) * 64 + f] + wv[3] * Sl[(g4 * 4 + 3) * 64 + f];
    }
    U2[idx] = f2bf(alpha * s);
  }
}

// ---------------------------------------------------------------------------
// Fused main kernel. Block = 16 tokens, 4 waves. Phase 1: waves split K
// (1024 cols each), per-lane direct H loads, explicit ring-buffer software
// pipeline (H depth-3, W depth-2), no barriers; LDS reduce of 4 partials.
// Phase 2: swapped-operand MFMA so each lane owns 4 consecutive output
// columns -> f32x4 residual load + f32x4 nontemporal store.
// ---------------------------------------------------------------------------
__global__ __launch_bounds__(256, 4) void main_kernel(
    const float* __restrict__ H, const unsigned short* __restrict__ Wd2,
    const unsigned short* __restrict__ U2, float* __restrict__ Out) {
  const int blk = blockIdx.x;
  const int b = blk >> 8;
  const int t = blk & 255;
  const int row0 = b * LSEQ + t * TM;

  const int tid = threadIdx.x;
  const int w = tid >> 6, l = tid & 63, lr = l & 15, lq = l >> 4;

  __shared__ float Fp[4][TM][65];
  __shared__ unsigned short Fb[TM][72];

  // ---------------- Phase 1 ----------------
  const float* ha = H + (size_t)(row0 + lr) * D_MODEL + w * 1024 + lq * 8;
  const unsigned short* wb = Wd2 + (size_t)w * 65536 + l * 8;

  f32x4 hb[3][2];
  bf16x8 wf[2][4];
#pragma unroll
  for (int s = 0; s < 3; ++s) {
    hb[s][0] = *(const f32x4*)(ha + s * 32);
    hb[s][1] = *(const f32x4*)(ha + s * 32 + 4);
  }
#pragma unroll
  for (int s = 0; s < 2; ++s)
#pragma unroll
    for (int nf = 0; nf < 4; ++nf)
      wf[s][nf] = *(const bf16x8*)(wb + s * 2048 + nf * 512);

  f32x4 acc[4];
#pragma unroll
  for (int nf = 0; nf < 4; ++nf) acc[nf] = (f32x4){0, 0, 0, 0};

#pragma unroll
  for (int s = 0; s < 32; ++s) {
    bf16x8 afr = cvt8(hb[s % 3][0], hb[s % 3][1]);
#pragma unroll
    for (int nf = 0; nf < 4; ++nf)
      acc[nf] = __builtin_amdgcn_mfma_f32_16x16x32_bf16(afr, wf[s & 1][nf], acc[nf], 0, 0, 0);
    if (s + 3 < 32) {
      hb[s % 3][0] = *(const f32x4*)(ha + (s + 3) * 32);
      hb[s % 3][1] = *(const f32x4*)(ha + (s + 3) * 32 + 4);
    }
    if (s + 2 < 32) {
#pragma unroll
      for (int nf = 0; nf < 4; ++nf)
        wf[s & 1][nf] = *(const bf16x8*)(wb + (s + 2) * 2048 + nf * 512);
    }
  }

  // partial F -> LDS (D layout: col=lane&15 -> fiber, row=4*lq+rr -> token)
#pragma unroll
  for (int nf = 0; nf < 4; ++nf)
#pragma unroll
    for (int rr = 0; rr < 4; ++rr)
      Fp[w][lq * 4 + rr][nf * 16 + lr] = acc[nf][rr];
  __syncthreads();

#pragma unroll
  for (int q = 0; q < 4; ++q) {
    int ee = tid + q * 256;
    int rrow = ee >> 6, ccol = ee & 63;
    float s2 = Fp[0][rrow][ccol] + Fp[1][rrow][ccol] +
               Fp[2][rrow][ccol] + Fp[3][rrow][ccol];
    Fb[rrow][ccol] = f2bf(s2);
  }
  __syncthreads();

  // ---------------- Phase 2 (swapped operands) ----------------
  bf16x8 fb0 = *(const bf16x8*)(&Fb[lr][lq * 8]);        // F[token=lr][g=lq*8+j]
  bf16x8 fb1 = *(const bf16x8*)(&Fb[lr][32 + lq * 8]);

  const unsigned short* ub = U2 + (((size_t)b * 256 + w * 64) * 64 + l) * 16;
  const size_t obase = (size_t)(row0 + lr) * D_MODEL + w * 1024 + lq * 4;

  bf16x8 u0r[2], u1r[2];
  f32x4 hr[2];
#pragma unroll
  for (int q = 0; q < 2; ++q) {
    u0r[q] = *(const bf16x8*)(ub + q * 1024);
    u1r[q] = *(const bf16x8*)(ub + q * 1024 + 8);
    hr[q]  = *(const f32x4*)(H + obase + q * 16);
  }

#pragma unroll
  for (int nf = 0; nf < 64; ++nf) {
    f32x4 c = {0, 0, 0, 0};
    c = __builtin_amdgcn_mfma_f32_16x16x32_bf16(u0r[nf & 1], fb0, c, 0, 0, 0);
    c = __builtin_amdgcn_mfma_f32_16x16x32_bf16(u1r[nf & 1], fb1, c, 0, 0, 0);
    f32x4 r = hr[nf & 1];
    if (nf + 2 < 64) {
      u0r[nf & 1] = *(const bf16x8*)(ub + (nf + 2) * 1024);
      u1r[nf & 1] = *(const bf16x8*)(ub + (nf + 2) * 1024 + 8);
      hr[nf & 1]  = *(const f32x4*)(H + obase + (nf + 2) * 16);
    }
    f32x4 v = r + c;
    __builtin_nontemporal_store(v, (f32x4*)(Out + obase + nf * 16));
  }
}

// ---------------------------------------------------------------------------
extern "C" void kernel_launch(void* const* d_in, const int* in_sizes, int n_in,
                              void* d_out, int out_size, void* d_ws, size_t ws_size,
                              hipStream_t stream) {
  const float* h_t    = (const float*)d_in[0];
  // d_in[1] = z0 (unused by the reference)
  const float* A_u    = (const float*)d_in[2];
  const float* alpha  = (const float*)d_in[3];
  const float* W_down = (const float*)d_in[4];
  const float* W_up   = (const float*)d_in[5];
  float* out = (float*)d_out;

  char* ws = (char*)d_ws;
  float*          S   = (float*)ws;                              // 64 KiB
  unsigned short* Wd2 = (unsigned short*)(ws + 65536);           // 512 KiB
  unsigned short* U2  = (unsigned short*)(ws + 65536 + 524288);  // 2 MiB

  cayley_kernel<<<NBATCH, 256, 0, stream>>>(A_u, S);
  prep_kernel<<<1024 + 4096, 256, 0, stream>>>(W_down, W_up, S, alpha, Wd2, U2);
  main_kernel<<<NBATCH * TILES, 256, 0, stream>>>(h_t, Wd2, U2, out);
}